// Round 5
// baseline (1146.681 us; speedup 1.0000x reference)
//
#include <hip/hip_runtime.h>
#include <stdint.h>

#define TT 512
#define BB 4096
#define NTILE 256
#define LOG2E 1.4426950408889634f

typedef _Float16 half8_t __attribute__((ext_vector_type(8)));
typedef __fp16 fp16x2_t __attribute__((ext_vector_type(2)));
typedef float f32x4 __attribute__((ext_vector_type(4)));

union FragU { uint4 u4; half8_t h8; };
union PkU { fp16x2_t h2; unsigned int u; };

__device__ __forceinline__ float rcp_(float x){ return __builtin_amdgcn_rcpf(x); }
__device__ __forceinline__ float exp2_(float x){ return __builtin_amdgcn_exp2f(x); }
__device__ __forceinline__ float elu_(float x){ return x > 0.0f ? x : (exp2_(x * LOG2E) - 1.0f); }
__device__ __forceinline__ int mini_(int a, int b){ return a < b ? a : b; }
__device__ __forceinline__ float maskhi_(float x){ return __uint_as_float(__float_as_uint(x) & 0xFFFFE000u); }
__device__ __forceinline__ unsigned int pkrtz_(float a, float b){
    PkU p; p.h2 = __builtin_amdgcn_cvt_pkrtz(a, b); return p.u;
}

__device__ __forceinline__ f32x4 MFMA(half8_t a, half8_t b, f32x4 c) {
    return __builtin_amdgcn_mfma_f32_16x16x32_f16(a, b, c, 0, 0, 0);
}

__device__ __forceinline__ f32x4 ld4_(const float* p){ return *(const f32x4*)p; }

// pack 8 f32 -> 8 f16 with scale (A-fragment slice; row = lane&15, k = 8*(lane>>4)+e)
__device__ __forceinline__ half8_t packA8s(const float* s, float sc) {
    half8_t h;
#pragma unroll
    for (int k = 0; k < 8; ++k) h[k] = (_Float16)(s[k] * sc);
    return h;
}

// Gate activations. Inputs PRESCALED: i,f,o rows by log2e; g rows by 2*log2e.
// sigmoid(x) = rcp(1 + exp2(-x*log2e)); tanh(x) = 2*rcp(1+exp2(-2x*log2e)) - 1.
__device__ __forceinline__ void cell4_(f32x4 gi, f32x4 gf, f32x4 gg, f32x4 go,
                                       f32x4& c, f32x4& h) {
#pragma unroll
    for (int r = 0; r < 4; ++r) {
        float I = rcp_(1.0f + exp2_(-gi[r]));
        float F = rcp_(1.0f + exp2_(-gf[r]));
        float G = fmaf(2.0f, rcp_(1.0f + exp2_(-gg[r])), -1.0f);
        float O = rcp_(1.0f + exp2_(-go[r]));
        float cc = fmaf(F, c[r], I * G);
        c[r] = cc;
        float th = fmaf(2.0f, rcp_(1.0f + exp2_(cc * (-2.0f * LOG2E))), -1.0f);
        h[r] = O * th;
    }
}

// h -> fp16 hi (exact mantissa truncation) + fp16 residual lo
__device__ __forceinline__ void packHL_(const f32x4 h, uint2& hh, uint2& hl) {
    float m0 = maskhi_(h[0]), m1 = maskhi_(h[1]), m2 = maskhi_(h[2]), m3 = maskhi_(h[3]);
    hh.x = pkrtz_(m0, m1);          hh.y = pkrtz_(m2, m3);
    hl.x = pkrtz_(h[0]-m0, h[1]-m1); hl.y = pkrtz_(h[2]-m2, h[3]-m3);
}

// Per-wave LDS h-exchange block (1536 B each; 16 cols x 80B used).
// Col b: bytes [0..31]=hi units 0..15, [32..63]=lo units 0..15.
// Write: lane(q,b) hh -> b*80+q*8, hl -> +32.  Read: lane(q,b) b128 at b*80+q*16
// == [hi u0-7 | hi u8-15 | lo u0-7 | lo u8-15] (HW-verified round-2 B-fragment:
// col=b, k=8q+e over K=32=[h_hi;h_lo]).
//
// 16 chain-waves per 1024-thread WG -> 4 waves per SIMD (waves round-robin
// across the CU's 4 SIMDs) so independent chains hide each other's stalls.

// ---------------- phase A: layer 0 (input dim 1), both directions ----------------
struct PA {
    const float *x;
    const float *WihF, *WhhF, *bihF, *bhhF;
    const float *WihB, *WhhB, *bihB, *bhhB;
    char* ws;   // [tile][t][1KB]: per (tile,t): [f u0-15 hi | b u0-15 hi] as halfs
};

__global__ __launch_bounds__(1024) void phaseA_k(PA p) {
    __shared__ uint4 lds4[16 * 96];   // 16 waves x 1536 B
    const int lane = threadIdx.x & 63;
    const int wv   = threadIdx.x >> 6;
    char* lds = (char*)lds4 + wv * 1536;
    const int q = lane >> 4, b = lane & 15;
    const int chain = blockIdx.x * 16 + wv;
    const int tile = chain >> 1, dir = chain & 1;

    const float* Wih = dir ? p.WihB : p.WihF;
    const float* Whh = dir ? p.WhhB : p.WhhF;
    const float* bih = dir ? p.bihB : p.bihF;
    const float* bhh = dir ? p.bhhB : p.bhhF;

    const float SC0 = LOG2E, SC1 = LOG2E, SC2 = 2.0f*LOG2E, SC3 = LOG2E;

    // A = [Whh | Whh] over K=32 (hi;lo halves use same weights)
    half8_t whh0 = packA8s(Whh + (     b)*16 + 8*(q&1), SC0);
    half8_t whh1 = packA8s(Whh + (16 + b)*16 + 8*(q&1), SC1);
    half8_t whh2 = packA8s(Whh + (32 + b)*16 + 8*(q&1), SC2);
    half8_t whh3 = packA8s(Whh + (48 + b)*16 + 8*(q&1), SC3);

    f32x4 bias0 = (ld4_(bih +      4*q) + ld4_(bhh +      4*q)) * SC0;
    f32x4 bias1 = (ld4_(bih + 16 + 4*q) + ld4_(bhh + 16 + 4*q)) * SC1;
    f32x4 bias2 = (ld4_(bih + 32 + 4*q) + ld4_(bhh + 32 + 4*q)) * SC2;
    f32x4 bias3 = (ld4_(bih + 48 + 4*q) + ld4_(bhh + 48 + 4*q)) * SC3;

    f32x4 wihx0 = ld4_(Wih +      4*q) * SC0;   // Wih0 is [64 x 1]
    f32x4 wihx1 = ld4_(Wih + 16 + 4*q) * SC1;
    f32x4 wihx2 = ld4_(Wih + 32 + 4*q) * SC2;
    f32x4 wihx3 = ld4_(Wih + 48 + 4*q) * SC3;

    const int wr = b*80 + q*8;
    const int rd = b*80 + q*16;
    { uint2 z; z.x = 0u; z.y = 0u;
      *(uint2*)(lds + wr) = z; *(uint2*)(lds + wr + 32) = z; }
    __builtin_amdgcn_wave_barrier();

    f32x4 c = {0.f,0.f,0.f,0.f}, h = {0.f,0.f,0.f,0.f};

    const char* xbase = (const char*)p.x + (size_t)tile*16*TT*4;  // uniform
    const int   xoff  = b*TT*4;                                   // invariant voffset
    char*       wsbase = p.ws + (size_t)tile*TT*1024;             // uniform
    const int   woff  = b*64 + dir*32 + q*8;

    auto xld = [&](int u)->float {
        int s = mini_(u, TT-1);
        int t = dir ? (TT-1-s) : s;
        return *(const float*)(xbase + (size_t)t*4 + xoff);
    };

    auto step = [&](float xv, int t) {
        FragU hf; hf.u4 = *(const uint4*)(lds + rd);
        f32x4 a0 = bias0 + wihx0 * xv;
        f32x4 a1 = bias1 + wihx1 * xv;
        f32x4 a2 = bias2 + wihx2 * xv;
        f32x4 a3 = bias3 + wihx3 * xv;
        a0 = MFMA(whh0, hf.h8, a0);
        a1 = MFMA(whh1, hf.h8, a1);
        a2 = MFMA(whh2, hf.h8, a2);
        a3 = MFMA(whh3, hf.h8, a3);
        cell4_(a0, a1, a2, a3, c, h);
        uint2 hh, hl; packHL_(h, hh, hl);
        *(uint2*)(lds + wr) = hh;
        *(uint2*)(lds + wr + 32) = hl;
        *(uint2*)(wsbase + (size_t)t*1024 + woff) = hh;
        __builtin_amdgcn_wave_barrier();
    };

    float xv0 = xld(0), xv1 = xld(1), xv2 = xld(2), xv3 = xld(3);
    for (int s = 0; s < TT; s += 4) {
        const int t0 = dir ? (TT-1-s) : s;
        const int d  = dir ? -1 : 1;
        step(xv0, t0      ); xv0 = xld(s+4);
        step(xv1, t0 + d  ); xv1 = xld(s+5);
        step(xv2, t0 + 2*d); xv2 = xld(s+6);
        step(xv3, t0 + 3*d); xv3 = xld(s+7);
    }
}

// ---------------- phase B: layer 1 (input dim 32 from ws), both directions ----------------
struct PB {
    const float *WihF, *WhhF, *bihF, *bhhF;
    const float *WihB, *WhhB, *bihB, *bhhB;
    const char* ws;
    float* hT;   // [dir][tile][b][16] f32
};

__global__ __launch_bounds__(1024) void phaseB_k(PB p) {
    __shared__ uint4 lds4[16 * 96];
    const int lane = threadIdx.x & 63;
    const int wv   = threadIdx.x >> 6;
    char* lds = (char*)lds4 + wv * 1536;
    const int q = lane >> 4, b = lane & 15;
    const int chain = blockIdx.x * 16 + wv;
    const int tile = chain >> 1, dir = chain & 1;

    const float* Wih = dir ? p.WihB : p.WihF;
    const float* Whh = dir ? p.WhhB : p.WhhF;
    const float* bih = dir ? p.bihB : p.bihF;
    const float* bhh = dir ? p.bhhB : p.bhhF;

    const float SC0 = LOG2E, SC1 = LOG2E, SC2 = 2.0f*LOG2E, SC3 = LOG2E;

    half8_t wih0 = packA8s(Wih + (     b)*32 + 8*q, SC0);  // K=32 = [h0f;h0b]
    half8_t wih1 = packA8s(Wih + (16 + b)*32 + 8*q, SC1);
    half8_t wih2 = packA8s(Wih + (32 + b)*32 + 8*q, SC2);
    half8_t wih3 = packA8s(Wih + (48 + b)*32 + 8*q, SC3);

    half8_t whh0 = packA8s(Whh + (     b)*16 + 8*(q&1), SC0);
    half8_t whh1 = packA8s(Whh + (16 + b)*16 + 8*(q&1), SC1);
    half8_t whh2 = packA8s(Whh + (32 + b)*16 + 8*(q&1), SC2);
    half8_t whh3 = packA8s(Whh + (48 + b)*16 + 8*(q&1), SC3);

    f32x4 bias0 = (ld4_(bih +      4*q) + ld4_(bhh +      4*q)) * SC0;
    f32x4 bias1 = (ld4_(bih + 16 + 4*q) + ld4_(bhh + 16 + 4*q)) * SC1;
    f32x4 bias2 = (ld4_(bih + 32 + 4*q) + ld4_(bhh + 32 + 4*q)) * SC2;
    f32x4 bias3 = (ld4_(bih + 48 + 4*q) + ld4_(bhh + 48 + 4*q)) * SC3;

    const int wr = b*80 + q*8;
    const int rd = b*80 + q*16;
    { uint2 z; z.x = 0u; z.y = 0u;
      *(uint2*)(lds + wr) = z; *(uint2*)(lds + wr + 32) = z; }
    __builtin_amdgcn_wave_barrier();

    f32x4 c = {0.f,0.f,0.f,0.f}, h = {0.f,0.f,0.f,0.f};

    const char* wsbase = p.ws + (size_t)tile*TT*1024;  // uniform
    const int   xoff   = b*64 + q*16;                  // invariant voffset

    auto xld = [&](int u)->uint4 {
        int s = mini_(u, TT-1);
        int t = dir ? (TT-1-s) : s;
        return *(const uint4*)(wsbase + (size_t)t*1024 + xoff);
    };

    auto step = [&](uint4 xin) {
        FragU xf; xf.u4 = xin;
        FragU hf; hf.u4 = *(const uint4*)(lds + rd);
        f32x4 a0 = MFMA(wih0, xf.h8, bias0);
        f32x4 a1 = MFMA(wih1, xf.h8, bias1);
        f32x4 a2 = MFMA(wih2, xf.h8, bias2);
        f32x4 a3 = MFMA(wih3, xf.h8, bias3);
        a0 = MFMA(whh0, hf.h8, a0);
        a1 = MFMA(whh1, hf.h8, a1);
        a2 = MFMA(whh2, hf.h8, a2);
        a3 = MFMA(whh3, hf.h8, a3);
        cell4_(a0, a1, a2, a3, c, h);
        uint2 hh, hl; packHL_(h, hh, hl);
        *(uint2*)(lds + wr) = hh;
        *(uint2*)(lds + wr + 32) = hl;
        __builtin_amdgcn_wave_barrier();
    };

    uint4 xb0 = xld(0), xb1 = xld(1), xb2 = xld(2), xb3 = xld(3);
    for (int s = 0; s < TT; s += 4) {
        step(xb0); xb0 = xld(s+4);
        step(xb1); xb1 = xld(s+5);
        step(xb2); xb2 = xld(s+6);
        step(xb3); xb3 = xld(s+7);
    }

    float* hp = p.hT + ((size_t)(dir*NTILE + tile)*16 + b)*16 + 4*q;
    *(f32x4*)hp = h;
}

// ---------------- phase C: MLP head ----------------
struct PC {
    const float* hT;
    const float *W1, *b1, *W2, *b2;
    float* out;
};

__global__ __launch_bounds__(64) void head_k(PC p) {
    const int B = blockIdx.x * 64 + threadIdx.x;
    const int tile = B >> 4, b = B & 15;
    const float* hf = p.hT + ((size_t)tile*16 + b)*16;
    const float* hb = p.hT + ((size_t)(NTILE + tile)*16 + b)*16;

    float z0[32];
#pragma unroll
    for (int k = 0; k < 16; ++k) z0[k] = elu_(hb[k]);       // feat = [hT_b, hT_f]
#pragma unroll
    for (int k = 0; k < 16; ++k) z0[16+k] = elu_(hf[k]);

    float z1[25];
#pragma unroll
    for (int o = 0; o < 25; ++o) {
        float a = p.b1[o];
#pragma unroll
        for (int k = 0; k < 32; ++k) a = fmaf(p.W1[o*32 + k], z0[k], a);
        z1[o] = elu_(a);
    }
#pragma unroll
    for (int o = 0; o < 20; ++o) {
        float a = p.b2[o];
#pragma unroll
        for (int k = 0; k < 25; ++k) a = fmaf(p.W2[o*25 + k], z1[k], a);
        p.out[(size_t)B*20 + o] = elu_(a);
    }
}

extern "C" void kernel_launch(void* const* d_in, const int* in_sizes, int n_in,
                              void* d_out, int out_size, void* d_ws, size_t ws_size,
                              hipStream_t stream) {
    (void)in_sizes; (void)n_in; (void)out_size;

    const size_t frag_bytes = (size_t)NTILE * TT * 1024;                   // 128 MiB
    const size_t hT_bytes   = (size_t)2 * NTILE * 16 * 16 * sizeof(float); // 512 KiB
    size_t hT_off = (ws_size >= frag_bytes + hT_bytes) ? frag_bytes
                                                       : (ws_size - hT_bytes);
    char* ws = (char*)d_ws;
    float* hT = (float*)(ws + hT_off);

    PA pa;
    pa.x = (const float*)d_in[0];
    pa.WihF = (const float*)d_in[1];  pa.WhhF = (const float*)d_in[2];
    pa.bihF = (const float*)d_in[3];  pa.bhhF = (const float*)d_in[4];
    pa.WihB = (const float*)d_in[5];  pa.WhhB = (const float*)d_in[6];
    pa.bihB = (const float*)d_in[7];  pa.bhhB = (const float*)d_in[8];
    pa.ws = ws;
    hipLaunchKernelGGL(phaseA_k, dim3(32), dim3(1024), 0, stream, pa);

    PB pb;
    pb.WihF = (const float*)d_in[9];   pb.WhhF = (const float*)d_in[10];
    pb.bihF = (const float*)d_in[11];  pb.bhhF = (const float*)d_in[12];
    pb.WihB = (const float*)d_in[13];  pb.WhhB = (const float*)d_in[14];
    pb.bihB = (const float*)d_in[15];  pb.bhhB = (const float*)d_in[16];
    pb.ws = ws; pb.hT = hT;
    hipLaunchKernelGGL(phaseB_k, dim3(32), dim3(1024), 0, stream, pb);

    PC pc;
    pc.hT = hT;
    pc.W1 = (const float*)d_in[17]; pc.b1 = (const float*)d_in[18];
    pc.W2 = (const float*)d_in[19]; pc.b2 = (const float*)d_in[20];
    pc.out = (float*)d_out;
    hipLaunchKernelGGL(head_k, dim3(BB/64), dim3(64), 0, stream, pc);
}

// Round 6
// 456.004 us; speedup vs baseline: 2.5146x; 2.5146x over previous
//
#include <hip/hip_runtime.h>
#include <stdint.h>

#define TT 512
#define BB 4096
#define NTILE 256
#define LOG2E 1.4426950408889634f

typedef _Float16 half8_t __attribute__((ext_vector_type(8)));
typedef __fp16 fp16x2_t __attribute__((ext_vector_type(2)));
typedef float f32x4 __attribute__((ext_vector_type(4)));

union FragU { uint4 u4; half8_t h8; };
union PkU { fp16x2_t h2; unsigned int u; };

__device__ __forceinline__ float rcp_(float x){ return __builtin_amdgcn_rcpf(x); }
__device__ __forceinline__ float exp2_(float x){ return __builtin_amdgcn_exp2f(x); }
__device__ __forceinline__ float elu_(float x){ return x > 0.0f ? x : (exp2_(x * LOG2E) - 1.0f); }
__device__ __forceinline__ int mini_(int a, int b){ return a < b ? a : b; }
__device__ __forceinline__ float maskhi_(float x){ return __uint_as_float(__float_as_uint(x) & 0xFFFFE000u); }
__device__ __forceinline__ unsigned int pkrtz_(float a, float b){
    PkU p; p.h2 = __builtin_amdgcn_cvt_pkrtz(a, b); return p.u;
}

__device__ __forceinline__ f32x4 MFMA(half8_t a, half8_t b, f32x4 c) {
    return __builtin_amdgcn_mfma_f32_16x16x32_f16(a, b, c, 0, 0, 0);
}

__device__ __forceinline__ f32x4 ld4_(const float* p){ return *(const f32x4*)p; }

// pack 8 f32 -> 8 f16 with scale (A-fragment slice; row = lane&15, k = 8*(lane>>4)+e)
__device__ __forceinline__ half8_t packA8s(const float* s, float sc) {
    half8_t h;
#pragma unroll
    for (int k = 0; k < 8; ++k) h[k] = (_Float16)(s[k] * sc);
    return h;
}

// Pair-wave sync: drain LDS writes, then workgroup barrier (2 waves).
// NOT __syncthreads() — that drains vmcnt(0) too, serializing the ws stores.
__device__ __forceinline__ void psync_() {
    asm volatile("s_waitcnt lgkmcnt(0)" ::: "memory");
    __builtin_amdgcn_s_barrier();
}

// Cell update for 2 units, always C-regs 0,1 (wave1's A-row permute guarantees
// its units land there). Inputs PRESCALED: i,f,o by log2e; g by 2*log2e.
__device__ __forceinline__ void cell2_(const f32x4 ai, const f32x4 af,
                                       const f32x4 ag, const f32x4 ao,
                                       float& c0, float& c1, float& h0, float& h1) {
    float I0 = rcp_(1.0f + exp2_(-ai[0]));
    float F0 = rcp_(1.0f + exp2_(-af[0]));
    float G0 = fmaf(2.0f, rcp_(1.0f + exp2_(-ag[0])), -1.0f);
    float O0 = rcp_(1.0f + exp2_(-ao[0]));
    c0 = fmaf(F0, c0, I0 * G0);
    h0 = O0 * fmaf(2.0f, rcp_(1.0f + exp2_(c0 * (-2.0f * LOG2E))), -1.0f);

    float I1 = rcp_(1.0f + exp2_(-ai[1]));
    float F1 = rcp_(1.0f + exp2_(-af[1]));
    float G1 = fmaf(2.0f, rcp_(1.0f + exp2_(-ag[1])), -1.0f);
    float O1 = rcp_(1.0f + exp2_(-ao[1]));
    c1 = fmaf(F1, c1, I1 * G1);
    h1 = O1 * fmaf(2.0f, rcp_(1.0f + exp2_(c1 * (-2.0f * LOG2E))), -1.0f);
}

__device__ __forceinline__ f32x4 swz23_(f32x4 v, int w) {
    // wave1: [2,3,0,1] so C-in matches its gate-row permute (row ^ 2)
    if (w) { f32x4 r; r[0]=v[2]; r[1]=v[3]; r[2]=v[0]; r[3]=v[1]; return r; }
    return v;
}

// LDS h-exchange per chain: double-buffered 1280 B regions, col b at b*80:
// bytes [0..31] hi fp16 units 0..15, [32..63] lo residual. Lane (q,b) of wave w
// writes units u0=4q+2w,u0+1 (b32 at b*80+u0*2, +32); reads B-frag b128 at
// b*80+q*16 = [hi u0-7|hi u8-15|lo u0-7|lo u8-15] (HW-verified round-2 layout,
// col=b, k=8q+e over K=32=[h_hi;h_lo]).

// ---------------- phase A: layer 0 (input dim 1), both directions ----------------
struct PA {
    const float *x;
    const float *WihF, *WhhF, *bihF, *bhhF;
    const float *WihB, *WhhB, *bihB, *bhhB;
    char* ws;   // [tile][t][1KB]: col b: bytes 0-31 = fwd units 0-15 hi fp16, 32-63 = bwd
};

__global__ __launch_bounds__(128) void phaseA_k(PA p) {
    __shared__ uint4 lds4[2 * 80];   // 2 buffers x 1280 B
    char* ldsbase = (char*)lds4;
    const int tid  = threadIdx.x;
    const int lane = tid & 63;
    const int w    = __builtin_amdgcn_readfirstlane(tid >> 6);  // wave id in pair
    const int q = lane >> 4, b = lane & 15;
    const int chain = blockIdx.x;
    const int tile = chain >> 1, dir = chain & 1;
    const int br = w ? (b ^ 2) : b;   // A-row permute for wave1

    const float* Wih = dir ? p.WihB : p.WihF;
    const float* Whh = dir ? p.WhhB : p.WhhF;
    const float* bih = dir ? p.bihB : p.bihF;
    const float* bhh = dir ? p.bhhB : p.bhhF;

    const float SC0 = LOG2E, SC1 = LOG2E, SC2 = 2.0f*LOG2E, SC3 = LOG2E;

    // A = [Whh | Whh] over K=32 (hi;lo halves use same weights)
    half8_t whh0 = packA8s(Whh + (     br)*16 + 8*(q&1), SC0);
    half8_t whh1 = packA8s(Whh + (16 + br)*16 + 8*(q&1), SC1);
    half8_t whh2 = packA8s(Whh + (32 + br)*16 + 8*(q&1), SC2);
    half8_t whh3 = packA8s(Whh + (48 + br)*16 + 8*(q&1), SC3);

    f32x4 bias0 = swz23_((ld4_(bih +      4*q) + ld4_(bhh +      4*q)) * SC0, w);
    f32x4 bias1 = swz23_((ld4_(bih + 16 + 4*q) + ld4_(bhh + 16 + 4*q)) * SC1, w);
    f32x4 bias2 = swz23_((ld4_(bih + 32 + 4*q) + ld4_(bhh + 32 + 4*q)) * SC2, w);
    f32x4 bias3 = swz23_((ld4_(bih + 48 + 4*q) + ld4_(bhh + 48 + 4*q)) * SC3, w);

    f32x4 wihx0 = swz23_(ld4_(Wih +      4*q) * SC0, w);   // Wih0 is [64 x 1]
    f32x4 wihx1 = swz23_(ld4_(Wih + 16 + 4*q) * SC1, w);
    f32x4 wihx2 = swz23_(ld4_(Wih + 32 + 4*q) * SC2, w);
    f32x4 wihx3 = swz23_(ld4_(Wih + 48 + 4*q) * SC3, w);

    const int u0  = 4*q + 2*w;          // this wave's unit pair
    const int rdo = b*80 + q*16;        // frag read offset
    const int wro = b*80 + u0*2;        // hi write offset (lo at +32)

    // zero buffer 0 (each lane covers its own slots; union = all bytes)
    *(unsigned int*)(ldsbase + wro) = 0u;
    *(unsigned int*)(ldsbase + wro + 32) = 0u;
    psync_();

    float c0 = 0.f, c1 = 0.f;

    const char* xbase = (const char*)p.x + (size_t)tile*16*TT*4;  // uniform
    const int   xoff  = b*TT*4;                                   // invariant voffset
    char*       wsbase = p.ws + (size_t)tile*TT*1024;             // uniform
    const int   woff  = b*64 + dir*32 + u0*2;

    auto xld = [&](int u)->float {
        int s = mini_(u, TT-1);
        int t = dir ? (TT-1-s) : s;
        return *(const float*)(xbase + (size_t)t*4 + xoff);
    };

    auto step = [&](float xv, int t, char* rb, char* wb) {
        FragU hf; hf.u4 = *(const uint4*)(rb + rdo);
        f32x4 a0 = bias0 + wihx0 * xv;
        f32x4 a1 = bias1 + wihx1 * xv;
        f32x4 a2 = bias2 + wihx2 * xv;
        f32x4 a3 = bias3 + wihx3 * xv;
        a0 = MFMA(whh0, hf.h8, a0);
        a1 = MFMA(whh1, hf.h8, a1);
        a2 = MFMA(whh2, hf.h8, a2);
        a3 = MFMA(whh3, hf.h8, a3);
        float h0, h1; cell2_(a0, a1, a2, a3, c0, c1, h0, h1);
        float m0 = maskhi_(h0), m1 = maskhi_(h1);
        unsigned int hh = pkrtz_(m0, m1), hl = pkrtz_(h0 - m0, h1 - m1);
        *(unsigned int*)(wb + wro) = hh;
        *(unsigned int*)(wb + wro + 32) = hl;
        *(unsigned int*)(wsbase + (size_t)t*1024 + woff) = hh;
        psync_();
    };

    char* bf0 = ldsbase; char* bf1 = ldsbase + 1280;
    float xv0 = xld(0), xv1 = xld(1), xv2 = xld(2), xv3 = xld(3);
    for (int s = 0; s < TT; s += 4) {
        const int t0 = dir ? (TT-1-s) : s;
        const int d  = dir ? -1 : 1;
        step(xv0, t0,       bf0, bf1); xv0 = xld(s+4);
        step(xv1, t0 + d,   bf1, bf0); xv1 = xld(s+5);
        step(xv2, t0 + 2*d, bf0, bf1); xv2 = xld(s+6);
        step(xv3, t0 + 3*d, bf1, bf0); xv3 = xld(s+7);
    }
}

// ---------------- phase B: layer 1 (input dim 32 from ws), both directions ----------------
struct PB {
    const float *WihF, *WhhF, *bihF, *bhhF;
    const float *WihB, *WhhB, *bihB, *bhhB;
    const char* ws;
    float* hT;   // [dir][tile][b][16] f32
};

__global__ __launch_bounds__(128) void phaseB_k(PB p) {
    __shared__ uint4 lds4[2 * 80];
    char* ldsbase = (char*)lds4;
    const int tid  = threadIdx.x;
    const int lane = tid & 63;
    const int w    = __builtin_amdgcn_readfirstlane(tid >> 6);
    const int q = lane >> 4, b = lane & 15;
    const int chain = blockIdx.x;
    const int tile = chain >> 1, dir = chain & 1;
    const int br = w ? (b ^ 2) : b;

    const float* Wih = dir ? p.WihB : p.WihF;
    const float* Whh = dir ? p.WhhB : p.WhhF;
    const float* bih = dir ? p.bihB : p.bihF;
    const float* bhh = dir ? p.bhhB : p.bhhF;

    const float SC0 = LOG2E, SC1 = LOG2E, SC2 = 2.0f*LOG2E, SC3 = LOG2E;

    half8_t wih0 = packA8s(Wih + (     br)*32 + 8*q, SC0);  // K=32 = [h0f;h0b]
    half8_t wih1 = packA8s(Wih + (16 + br)*32 + 8*q, SC1);
    half8_t wih2 = packA8s(Wih + (32 + br)*32 + 8*q, SC2);
    half8_t wih3 = packA8s(Wih + (48 + br)*32 + 8*q, SC3);

    half8_t whh0 = packA8s(Whh + (     br)*16 + 8*(q&1), SC0);
    half8_t whh1 = packA8s(Whh + (16 + br)*16 + 8*(q&1), SC1);
    half8_t whh2 = packA8s(Whh + (32 + br)*16 + 8*(q&1), SC2);
    half8_t whh3 = packA8s(Whh + (48 + br)*16 + 8*(q&1), SC3);

    f32x4 bias0 = swz23_((ld4_(bih +      4*q) + ld4_(bhh +      4*q)) * SC0, w);
    f32x4 bias1 = swz23_((ld4_(bih + 16 + 4*q) + ld4_(bhh + 16 + 4*q)) * SC1, w);
    f32x4 bias2 = swz23_((ld4_(bih + 32 + 4*q) + ld4_(bhh + 32 + 4*q)) * SC2, w);
    f32x4 bias3 = swz23_((ld4_(bih + 48 + 4*q) + ld4_(bhh + 48 + 4*q)) * SC3, w);

    const int u0  = 4*q + 2*w;
    const int rdo = b*80 + q*16;
    const int wro = b*80 + u0*2;

    *(unsigned int*)(ldsbase + wro) = 0u;
    *(unsigned int*)(ldsbase + wro + 32) = 0u;
    psync_();

    float c0 = 0.f, c1 = 0.f;
    float h0 = 0.f, h1 = 0.f;

    const char* wsbase = p.ws + (size_t)tile*TT*1024;  // uniform
    const int   xoff   = b*64 + q*16;                  // invariant voffset

    auto xld = [&](int u)->uint4 {
        int s = mini_(u, TT-1);
        int t = dir ? (TT-1-s) : s;
        return *(const uint4*)(wsbase + (size_t)t*1024 + xoff);
    };

    auto step = [&](uint4 xin, char* rb, char* wb) {
        FragU xf; xf.u4 = xin;
        FragU hf; hf.u4 = *(const uint4*)(rb + rdo);
        f32x4 a0 = MFMA(wih0, xf.h8, bias0);
        f32x4 a1 = MFMA(wih1, xf.h8, bias1);
        f32x4 a2 = MFMA(wih2, xf.h8, bias2);
        f32x4 a3 = MFMA(wih3, xf.h8, bias3);
        a0 = MFMA(whh0, hf.h8, a0);
        a1 = MFMA(whh1, hf.h8, a1);
        a2 = MFMA(whh2, hf.h8, a2);
        a3 = MFMA(whh3, hf.h8, a3);
        cell2_(a0, a1, a2, a3, c0, c1, h0, h1);
        float m0 = maskhi_(h0), m1 = maskhi_(h1);
        unsigned int hh = pkrtz_(m0, m1), hl = pkrtz_(h0 - m0, h1 - m1);
        *(unsigned int*)(wb + wro) = hh;
        *(unsigned int*)(wb + wro + 32) = hl;
        psync_();
    };

    char* bf0 = ldsbase; char* bf1 = ldsbase + 1280;
    uint4 xb0 = xld(0), xb1 = xld(1), xb2 = xld(2), xb3 = xld(3);
    for (int s = 0; s < TT; s += 4) {
        step(xb0, bf0, bf1); xb0 = xld(s+4);
        step(xb1, bf1, bf0); xb1 = xld(s+5);
        step(xb2, bf0, bf1); xb2 = xld(s+6);
        step(xb3, bf1, bf0); xb3 = xld(s+7);
    }

    // each lane writes its own unit pair (f32) — union over waves = all 16 units
    float* hp = p.hT + ((size_t)(dir*NTILE + tile)*16 + b)*16 + u0;
    hp[0] = h0; hp[1] = h1;
}

// ---------------- phase C: MLP head ----------------
struct PC {
    const float* hT;
    const float *W1, *b1, *W2, *b2;
    float* out;
};

__global__ __launch_bounds__(64) void head_k(PC p) {
    const int B = blockIdx.x * 64 + threadIdx.x;
    const int tile = B >> 4, b = B & 15;
    const float* hf = p.hT + ((size_t)tile*16 + b)*16;
    const float* hb = p.hT + ((size_t)(NTILE + tile)*16 + b)*16;

    float z0[32];
#pragma unroll
    for (int k = 0; k < 16; ++k) z0[k] = elu_(hb[k]);       // feat = [hT_b, hT_f]
#pragma unroll
    for (int k = 0; k < 16; ++k) z0[16+k] = elu_(hf[k]);

    float z1[25];
#pragma unroll
    for (int o = 0; o < 25; ++o) {
        float a = p.b1[o];
#pragma unroll
        for (int k = 0; k < 32; ++k) a = fmaf(p.W1[o*32 + k], z0[k], a);
        z1[o] = elu_(a);
    }
#pragma unroll
    for (int o = 0; o < 20; ++o) {
        float a = p.b2[o];
#pragma unroll
        for (int k = 0; k < 25; ++k) a = fmaf(p.W2[o*25 + k], z1[k], a);
        p.out[(size_t)B*20 + o] = elu_(a);
    }
}

extern "C" void kernel_launch(void* const* d_in, const int* in_sizes, int n_in,
                              void* d_out, int out_size, void* d_ws, size_t ws_size,
                              hipStream_t stream) {
    (void)in_sizes; (void)n_in; (void)out_size;

    const size_t frag_bytes = (size_t)NTILE * TT * 1024;                   // 128 MiB
    const size_t hT_bytes   = (size_t)2 * NTILE * 16 * 16 * sizeof(float); // 512 KiB
    size_t hT_off = (ws_size >= frag_bytes + hT_bytes) ? frag_bytes
                                                       : (ws_size - hT_bytes);
    char* ws = (char*)d_ws;
    float* hT = (float*)(ws + hT_off);

    PA pa;
    pa.x = (const float*)d_in[0];
    pa.WihF = (const float*)d_in[1];  pa.WhhF = (const float*)d_in[2];
    pa.bihF = (const float*)d_in[3];  pa.bhhF = (const float*)d_in[4];
    pa.WihB = (const float*)d_in[5];  pa.WhhB = (const float*)d_in[6];
    pa.bihB = (const float*)d_in[7];  pa.bhhB = (const float*)d_in[8];
    pa.ws = ws;
    hipLaunchKernelGGL(phaseA_k, dim3(NTILE*2), dim3(128), 0, stream, pa);

    PB pb;
    pb.WihF = (const float*)d_in[9];   pb.WhhF = (const float*)d_in[10];
    pb.bihF = (const float*)d_in[11];  pb.bhhF = (const float*)d_in[12];
    pb.WihB = (const float*)d_in[13];  pb.WhhB = (const float*)d_in[14];
    pb.bihB = (const float*)d_in[15];  pb.bhhB = (const float*)d_in[16];
    pb.ws = ws; pb.hT = hT;
    hipLaunchKernelGGL(phaseB_k, dim3(NTILE*2), dim3(128), 0, stream, pb);

    PC pc;
    pc.hT = hT;
    pc.W1 = (const float*)d_in[17]; pc.b1 = (const float*)d_in[18];
    pc.W2 = (const float*)d_in[19]; pc.b2 = (const float*)d_in[20];
    pc.out = (float*)d_out;
    hipLaunchKernelGGL(head_k, dim3(BB/64), dim3(64), 0, stream, pc);
}

// Round 7
// 308.088 us; speedup vs baseline: 3.7219x; 1.4801x over previous
//
#include <hip/hip_runtime.h>
#include <stdint.h>

#define TT 512
#define BB 4096
#define NT8 512   // tiles of 8 batch columns
#define LOG2E 1.4426950408889634f

typedef _Float16 half8_t __attribute__((ext_vector_type(8)));
typedef __fp16 fp16x2_t __attribute__((ext_vector_type(2)));
typedef float f32x4 __attribute__((ext_vector_type(4)));

union FragU { uint4 u4; half8_t h8; };
union PkU { fp16x2_t h2; unsigned int u; };

__device__ __forceinline__ float rcp_(float x){ return __builtin_amdgcn_rcpf(x); }
__device__ __forceinline__ float exp2_(float x){ return __builtin_amdgcn_exp2f(x); }
__device__ __forceinline__ float elu_(float x){ return x > 0.0f ? x : (exp2_(x * LOG2E) - 1.0f); }
__device__ __forceinline__ int mini_(int a, int b){ return a < b ? a : b; }
__device__ __forceinline__ float maskhi_(float x){ return __uint_as_float(__float_as_uint(x) & 0xFFFFE000u); }
__device__ __forceinline__ unsigned int pkrtz_(float a, float b){
    PkU p; p.h2 = __builtin_amdgcn_cvt_pkrtz(a, b); return p.u;
}

__device__ __forceinline__ f32x4 MFMA(half8_t a, half8_t b, f32x4 c) {
    return __builtin_amdgcn_mfma_f32_16x16x32_f16(a, b, c, 0, 0, 0);
}

__device__ __forceinline__ f32x4 ld4_(const float* p){ return *(const f32x4*)p; }

// pack 8 f32 -> 8 f16 with scale (A-fragment slice; row = lane&15, k = 8*(lane>>4)+e)
__device__ __forceinline__ half8_t packA8s(const float* s, float sc) {
    half8_t h;
#pragma unroll
    for (int k = 0; k < 8; ++k) h[k] = (_Float16)(s[k] * sc);
    return h;
}

// Cell update, 2 units per lane. Inputs PRESCALED: i,f,o by log2e; g by 2*log2e.
// sigmoid(x)=rcp(1+exp2(-x')); tanh(x)=2*rcp(1+exp2(-2x'))-1.
__device__ __forceinline__ void cell2s_(float gi0, float gf0, float gg0, float go0,
                                        float gi1, float gf1, float gg1, float go1,
                                        float& c0, float& c1, float& h0, float& h1) {
    float I0 = rcp_(1.0f + exp2_(-gi0));
    float F0 = rcp_(1.0f + exp2_(-gf0));
    float G0 = fmaf(2.0f, rcp_(1.0f + exp2_(-gg0)), -1.0f);
    float O0 = rcp_(1.0f + exp2_(-go0));
    c0 = fmaf(F0, c0, I0 * G0);
    h0 = O0 * fmaf(2.0f, rcp_(1.0f + exp2_(c0 * (-2.0f * LOG2E))), -1.0f);

    float I1 = rcp_(1.0f + exp2_(-gi1));
    float F1 = rcp_(1.0f + exp2_(-gf1));
    float G1 = fmaf(2.0f, rcp_(1.0f + exp2_(-gg1)), -1.0f);
    float O1 = rcp_(1.0f + exp2_(-go1));
    c1 = fmaf(F1, c1, I1 * G1);
    h1 = O1 * fmaf(2.0f, rcp_(1.0f + exp2_(c1 * (-2.0f * LOG2E))), -1.0f);
}

// Duplicate-column scheme (8 real cols per chain, B cols 8-15 ≡ cols 0-7):
// every lane addresses col c=b&7, so C[:,8+c]==C[:,c]; lane (q,b<8) keeps
// C-regs {0,1} = units 4q,4q+1; lane (q,b>=8) uses its own regs {2,3} =
// units 4q+2,4q+3. 2 units/lane -> 20 trans/step. No cross-lane traffic.
//
// Per-wave LDS (768 B): col c at c*80: bytes [0..31] hi fp16 units 0..15,
// [32..63] lo residual. Lane writes b32 hi at c*80+uu*2, lo at +32
// (uu = 4q + 2*(b>=8)). B-frag read: b128 at c*80+q*16 =
// [hi u0-7 | hi u8-15 | lo u0-7 | lo u8-15]  (K=32 = [h_hi; h_lo],
// HW-verified layout: col=lane&15 (dup via c), k=8q+e).

// ---------------- phase A: layer 0 (input dim 1), both directions ----------------
struct PA {
    const float *x;
    const float *WihF, *WhhF, *bihF, *bhhF;
    const float *WihB, *WhhB, *bihB, *bhhB;
    char* ws;   // [tile8][t][512B]: col c at c*64: [f u0-15 hi | b u0-15 hi] fp16
};

__global__ __launch_bounds__(256) void phaseA_k(PA p) {
    __shared__ uint4 lds4[4 * 48];   // 4 waves x 768 B
    const int tid = threadIdx.x;
    const int lane = tid & 63;
    const int wv   = tid >> 6;
    char* lds = (char*)lds4 + wv * 768;
    const int q = lane >> 4, b = lane & 15, c = b & 7;
    const bool hi8 = b >= 8;
    const int chain = blockIdx.x * 4 + wv;       // 1024 chains = 512 tiles x 2 dirs
    const int tile = chain >> 1, dir = chain & 1;

    const float* Wih = dir ? p.WihB : p.WihF;
    const float* Whh = dir ? p.WhhB : p.WhhF;
    const float* bih = dir ? p.bihB : p.bihF;
    const float* bhh = dir ? p.bhhB : p.bhhF;

    const float SC0 = LOG2E, SC1 = LOG2E, SC2 = 2.0f*LOG2E, SC3 = LOG2E;

    // A = [Whh | Whh] over K=32 (hi;lo halves use same weights); row = b (0-15)
    half8_t whh0 = packA8s(Whh + (     b)*16 + 8*(q&1), SC0);
    half8_t whh1 = packA8s(Whh + (16 + b)*16 + 8*(q&1), SC1);
    half8_t whh2 = packA8s(Whh + (32 + b)*16 + 8*(q&1), SC2);
    half8_t whh3 = packA8s(Whh + (48 + b)*16 + 8*(q&1), SC3);

    f32x4 bias0 = (ld4_(bih +      4*q) + ld4_(bhh +      4*q)) * SC0;
    f32x4 bias1 = (ld4_(bih + 16 + 4*q) + ld4_(bhh + 16 + 4*q)) * SC1;
    f32x4 bias2 = (ld4_(bih + 32 + 4*q) + ld4_(bhh + 32 + 4*q)) * SC2;
    f32x4 bias3 = (ld4_(bih + 48 + 4*q) + ld4_(bhh + 48 + 4*q)) * SC3;

    f32x4 wihx0 = ld4_(Wih +      4*q) * SC0;   // Wih0 is [64 x 1]
    f32x4 wihx1 = ld4_(Wih + 16 + 4*q) * SC1;
    f32x4 wihx2 = ld4_(Wih + 32 + 4*q) * SC2;
    f32x4 wihx3 = ld4_(Wih + 48 + 4*q) * SC3;

    const int uu  = 4*q + (hi8 ? 2 : 0);   // this lane's unit pair
    const int rdo = c*80 + q*16;           // frag read offset
    const int wro = c*80 + uu*2;           // hi write offset (lo at +32)

    { unsigned int* z = (unsigned int*)lds;       // zero bytes [0,640)
      for (int k = lane; k < 160; k += 64) z[k] = 0u; }
    __builtin_amdgcn_wave_barrier();

    float c0 = 0.f, c1 = 0.f;

    const char* xbase = (const char*)p.x + (size_t)tile*8*TT*4;   // uniform
    const int   xoff  = c*TT*4;                                   // invariant voffset
    char*       wsbase = p.ws + (size_t)tile*TT*512;              // uniform
    const int   woff  = c*64 + dir*32 + uu*2;

    auto xld = [&](int u)->float {
        int s = mini_(u, TT-1);
        int t = dir ? (TT-1-s) : s;
        return *(const float*)(xbase + (size_t)t*4 + xoff);
    };

    auto step = [&](float xv, int t) {
        FragU hf; hf.u4 = *(const uint4*)(lds + rdo);
        f32x4 a0 = bias0 + wihx0 * xv;
        f32x4 a1 = bias1 + wihx1 * xv;
        f32x4 a2 = bias2 + wihx2 * xv;
        f32x4 a3 = bias3 + wihx3 * xv;
        a0 = MFMA(whh0, hf.h8, a0);
        a1 = MFMA(whh1, hf.h8, a1);
        a2 = MFMA(whh2, hf.h8, a2);
        a3 = MFMA(whh3, hf.h8, a3);
        float gi0 = hi8 ? a0[2] : a0[0], gi1 = hi8 ? a0[3] : a0[1];
        float gf0 = hi8 ? a1[2] : a1[0], gf1 = hi8 ? a1[3] : a1[1];
        float gg0 = hi8 ? a2[2] : a2[0], gg1 = hi8 ? a2[3] : a2[1];
        float go0 = hi8 ? a3[2] : a3[0], go1 = hi8 ? a3[3] : a3[1];
        float h0, h1;
        cell2s_(gi0, gf0, gg0, go0, gi1, gf1, gg1, go1, c0, c1, h0, h1);
        float m0 = maskhi_(h0), m1 = maskhi_(h1);
        unsigned int hh = pkrtz_(m0, m1), hl = pkrtz_(h0 - m0, h1 - m1);
        *(unsigned int*)(lds + wro) = hh;
        *(unsigned int*)(lds + wro + 32) = hl;
        *(unsigned int*)(wsbase + (size_t)t*512 + woff) = hh;
        __builtin_amdgcn_wave_barrier();
    };

    float xv0 = xld(0), xv1 = xld(1), xv2 = xld(2), xv3 = xld(3);
    for (int s = 0; s < TT; s += 4) {
        const int t0 = dir ? (TT-1-s) : s;
        const int d  = dir ? -1 : 1;
        step(xv0, t0      ); xv0 = xld(s+4);
        step(xv1, t0 + d  ); xv1 = xld(s+5);
        step(xv2, t0 + 2*d); xv2 = xld(s+6);
        step(xv3, t0 + 3*d); xv3 = xld(s+7);
    }
}

// ---------------- phase B: layer 1 (input dim 32 from ws), both directions ----------------
struct PB {
    const float *WihF, *WhhF, *bihF, *bhhF;
    const float *WihB, *WhhB, *bihB, *bhhB;
    const char* ws;
    float* hT;   // [dir][tile8][c][16] f32
};

__global__ __launch_bounds__(256) void phaseB_k(PB p) {
    __shared__ uint4 lds4[4 * 48];
    const int tid = threadIdx.x;
    const int lane = tid & 63;
    const int wv   = tid >> 6;
    char* lds = (char*)lds4 + wv * 768;
    const int q = lane >> 4, b = lane & 15, c = b & 7;
    const bool hi8 = b >= 8;
    const int chain = blockIdx.x * 4 + wv;
    const int tile = chain >> 1, dir = chain & 1;

    const float* Wih = dir ? p.WihB : p.WihF;
    const float* Whh = dir ? p.WhhB : p.WhhF;
    const float* bih = dir ? p.bihB : p.bihF;
    const float* bhh = dir ? p.bhhB : p.bhhF;

    const float SC0 = LOG2E, SC1 = LOG2E, SC2 = 2.0f*LOG2E, SC3 = LOG2E;

    half8_t wih0 = packA8s(Wih + (     b)*32 + 8*q, SC0);  // K=32 = [h0f;h0b]
    half8_t wih1 = packA8s(Wih + (16 + b)*32 + 8*q, SC1);
    half8_t wih2 = packA8s(Wih + (32 + b)*32 + 8*q, SC2);
    half8_t wih3 = packA8s(Wih + (48 + b)*32 + 8*q, SC3);

    half8_t whh0 = packA8s(Whh + (     b)*16 + 8*(q&1), SC0);
    half8_t whh1 = packA8s(Whh + (16 + b)*16 + 8*(q&1), SC1);
    half8_t whh2 = packA8s(Whh + (32 + b)*16 + 8*(q&1), SC2);
    half8_t whh3 = packA8s(Whh + (48 + b)*16 + 8*(q&1), SC3);

    f32x4 bias0 = (ld4_(bih +      4*q) + ld4_(bhh +      4*q)) * SC0;
    f32x4 bias1 = (ld4_(bih + 16 + 4*q) + ld4_(bhh + 16 + 4*q)) * SC1;
    f32x4 bias2 = (ld4_(bih + 32 + 4*q) + ld4_(bhh + 32 + 4*q)) * SC2;
    f32x4 bias3 = (ld4_(bih + 48 + 4*q) + ld4_(bhh + 48 + 4*q)) * SC3;

    const int uu  = 4*q + (hi8 ? 2 : 0);
    const int rdo = c*80 + q*16;
    const int wro = c*80 + uu*2;

    { unsigned int* z = (unsigned int*)lds;
      for (int k = lane; k < 160; k += 64) z[k] = 0u; }
    __builtin_amdgcn_wave_barrier();

    float c0 = 0.f, c1 = 0.f;
    float h0 = 0.f, h1 = 0.f;

    const char* wsbase = p.ws + (size_t)tile*TT*512;   // uniform
    const int   xoff   = c*64 + q*16;                  // invariant voffset

    auto xld = [&](int u)->uint4 {
        int s = mini_(u, TT-1);
        int t = dir ? (TT-1-s) : s;
        return *(const uint4*)(wsbase + (size_t)t*512 + xoff);
    };

    auto step = [&](uint4 xin) {
        FragU xf; xf.u4 = xin;
        FragU hf; hf.u4 = *(const uint4*)(lds + rdo);
        f32x4 a0 = MFMA(wih0, xf.h8, bias0);
        f32x4 a1 = MFMA(wih1, xf.h8, bias1);
        f32x4 a2 = MFMA(wih2, xf.h8, bias2);
        f32x4 a3 = MFMA(wih3, xf.h8, bias3);
        a0 = MFMA(whh0, hf.h8, a0);
        a1 = MFMA(whh1, hf.h8, a1);
        a2 = MFMA(whh2, hf.h8, a2);
        a3 = MFMA(whh3, hf.h8, a3);
        float gi0 = hi8 ? a0[2] : a0[0], gi1 = hi8 ? a0[3] : a0[1];
        float gf0 = hi8 ? a1[2] : a1[0], gf1 = hi8 ? a1[3] : a1[1];
        float gg0 = hi8 ? a2[2] : a2[0], gg1 = hi8 ? a2[3] : a2[1];
        float go0 = hi8 ? a3[2] : a3[0], go1 = hi8 ? a3[3] : a3[1];
        cell2s_(gi0, gf0, gg0, go0, gi1, gf1, gg1, go1, c0, c1, h0, h1);
        float m0 = maskhi_(h0), m1 = maskhi_(h1);
        unsigned int hh = pkrtz_(m0, m1), hl = pkrtz_(h0 - m0, h1 - m1);
        *(unsigned int*)(lds + wro) = hh;
        *(unsigned int*)(lds + wro + 32) = hl;
        __builtin_amdgcn_wave_barrier();
    };

    uint4 xb0 = xld(0), xb1 = xld(1), xb2 = xld(2), xb3 = xld(3);
    for (int s = 0; s < TT; s += 4) {
        step(xb0); xb0 = xld(s+4);
        step(xb1); xb1 = xld(s+5);
        step(xb2); xb2 = xld(s+6);
        step(xb3); xb3 = xld(s+7);
    }

    // each lane writes its unit pair (f32x2) — union over lanes = all 16 units x 8 cols
    float* hp = p.hT + ((size_t)(dir*NT8 + tile)*8 + c)*16 + uu;
    float2 hv; hv.x = h0; hv.y = h1;
    *(float2*)hp = hv;
}

// ---------------- phase C: MLP head ----------------
struct PC {
    const float* hT;
    const float *W1, *b1, *W2, *b2;
    float* out;
};

__global__ __launch_bounds__(64) void head_k(PC p) {
    const int B = blockIdx.x * 64 + threadIdx.x;
    const int tile = B >> 3, c = B & 7;
    const float* hf = p.hT + ((size_t)(         tile)*8 + c)*16;
    const float* hb = p.hT + ((size_t)(NT8 + tile)*8 + c)*16;

    float z0[32];
#pragma unroll
    for (int k = 0; k < 16; ++k) z0[k] = elu_(hb[k]);       // feat = [hT_b, hT_f]
#pragma unroll
    for (int k = 0; k < 16; ++k) z0[16+k] = elu_(hf[k]);

    float z1[25];
#pragma unroll
    for (int o = 0; o < 25; ++o) {
        float a = p.b1[o];
#pragma unroll
        for (int k = 0; k < 32; ++k) a = fmaf(p.W1[o*32 + k], z0[k], a);
        z1[o] = elu_(a);
    }
#pragma unroll
    for (int o = 0; o < 20; ++o) {
        float a = p.b2[o];
#pragma unroll
        for (int k = 0; k < 25; ++k) a = fmaf(p.W2[o*25 + k], z1[k], a);
        p.out[(size_t)B*20 + o] = elu_(a);
    }
}

extern "C" void kernel_launch(void* const* d_in, const int* in_sizes, int n_in,
                              void* d_out, int out_size, void* d_ws, size_t ws_size,
                              hipStream_t stream) {
    (void)in_sizes; (void)n_in; (void)out_size;

    const size_t frag_bytes = (size_t)NT8 * TT * 512;                   // 128 MiB
    const size_t hT_bytes   = (size_t)2 * NT8 * 8 * 16 * sizeof(float); // 512 KiB
    size_t hT_off = (ws_size >= frag_bytes + hT_bytes) ? frag_bytes
                                                       : (ws_size - hT_bytes);
    char* ws = (char*)d_ws;
    float* hT = (float*)(ws + hT_off);

    PA pa;
    pa.x = (const float*)d_in[0];
    pa.WihF = (const float*)d_in[1];  pa.WhhF = (const float*)d_in[2];
    pa.bihF = (const float*)d_in[3];  pa.bhhF = (const float*)d_in[4];
    pa.WihB = (const float*)d_in[5];  pa.WhhB = (const float*)d_in[6];
    pa.bihB = (const float*)d_in[7];  pa.bhhB = (const float*)d_in[8];
    pa.ws = ws;
    hipLaunchKernelGGL(phaseA_k, dim3(256), dim3(256), 0, stream, pa);

    PB pb;
    pb.WihF = (const float*)d_in[9];   pb.WhhF = (const float*)d_in[10];
    pb.bihF = (const float*)d_in[11];  pb.bhhF = (const float*)d_in[12];
    pb.WihB = (const float*)d_in[13];  pb.WhhB = (const float*)d_in[14];
    pb.bihB = (const float*)d_in[15];  pb.bhhB = (const float*)d_in[16];
    pb.ws = ws; pb.hT = hT;
    hipLaunchKernelGGL(phaseB_k, dim3(256), dim3(256), 0, stream, pb);

    PC pc;
    pc.hT = hT;
    pc.W1 = (const float*)d_in[17]; pc.b1 = (const float*)d_in[18];
    pc.W2 = (const float*)d_in[19]; pc.b2 = (const float*)d_in[20];
    pc.out = (float*)d_out;
    hipLaunchKernelGGL(head_k, dim3(BB/64), dim3(64), 0, stream, pc);
}